// Round 8
// baseline (416.946 us; speedup 1.0000x reference)
//
#include <hip/hip_runtime.h>

#define NB   4
#define C_IN 256
#define CQD  64
#define NPT  4096
#define L2E  1.44269504088896f

typedef __attribute__((ext_vector_type(8)))  short bf16x8;
typedef __attribute__((ext_vector_type(4)))  float f32x4;
typedef __attribute__((ext_vector_type(16))) float f32x16;
typedef unsigned short u16;
typedef unsigned int   u32;

#define EXP2F(x)        __builtin_amdgcn_exp2f(x)
#define MFMA32(A,B,C)   __builtin_amdgcn_mfma_f32_16x16x32_bf16(A,B,C,0,0,0)
#define MFMA3216(A,B,C) __builtin_amdgcn_mfma_f32_32x32x16_bf16(A,B,C,0,0,0)

__device__ __forceinline__ u16 f2bf(float f) {          // RNE (cold paths)
    u32 u = __float_as_uint(f);
    u += 0x7fff + ((u >> 16) & 1);
    return (u16)(u >> 16);
}
// one v_perm: (bf16_trunc(hi)<<16) | bf16_trunc(lo)
__device__ __forceinline__ u32 pack_trunc(float lo, float hi) {
    return __builtin_amdgcn_perm(__float_as_uint(hi), __float_as_uint(lo), 0x07060302u);
}

// ---------------------------------------------------------------------------
// prep: pack wq|wk|wv into bf16 wbf[384][256], biases into bias[384]
// ---------------------------------------------------------------------------
__global__ void prep_kernel(
    const float* __restrict__ wq, const float* __restrict__ bq,
    const float* __restrict__ wk, const float* __restrict__ bk,
    const float* __restrict__ wv, const float* __restrict__ bv,
    u16* __restrict__ wbf, float* __restrict__ bias)
{
    const int gid = blockIdx.x*256 + threadIdx.x;
    if (gid < 384*256) {
        const int r = gid >> 8, c = gid & 255;
        const float v = (r < 64) ? wq[r*256 + c]
                      : (r < 128) ? wk[(r-64)*256 + c]
                                  : wv[(r-128)*256 + c];
        wbf[gid] = f2bf(v);
    } else if (gid < 384*256 + 384) {
        const int r = gid - 384*256;
        bias[r] = (r < 64) ? bq[r] : (r < 128) ? bk[r-64] : bv[r-128];
    }
}

// ---------------------------------------------------------------------------
// proj: MFMA pointwise projections, x read ONCE. Wave w owns tiles T=4*ot+w.
// grid (N/32, B), block 256.
// ---------------------------------------------------------------------------
union ProjShared {
    u16 x_t[32][264];                            // [n][c] bf16, stride 528B
    struct { u16 qk[32][136]; u16 vl[256][40]; } ep;
};

__global__ __launch_bounds__(256) void proj_kernel(
    const float* __restrict__ x, const u16* __restrict__ wbf,
    const float* __restrict__ bias,
    u16* __restrict__ qT, u16* __restrict__ kT, u16* __restrict__ vbf)
{
    __shared__ ProjShared sh;

    const int t  = threadIdx.x;
    const int n0 = blockIdx.x * 32;
    const int b  = blockIdx.y;

    {   // stage x tile transposed -> bf16 LDS
        const int ln = t & 31;
        const int cg = t >> 5;
        #pragma unroll
        for (int rr = 0; rr < 8; rr++) {
            const int c = 4*cg + 32*rr;
            const float f0 = x[((size_t)(b*C_IN + c+0))*NPT + n0 + ln];
            const float f1 = x[((size_t)(b*C_IN + c+1))*NPT + n0 + ln];
            const float f2 = x[((size_t)(b*C_IN + c+2))*NPT + n0 + ln];
            const float f3 = x[((size_t)(b*C_IN + c+3))*NPT + n0 + ln];
            ushort4 u4;
            u4.x = f2bf(f0); u4.y = f2bf(f1); u4.z = f2bf(f2); u4.w = f2bf(f3);
            *(ushort4*)&sh.x_t[ln][c] = u4;
        }
    }
    __syncthreads();

    const int w = t >> 6, l = t & 63, q = l >> 4, c16 = l & 15;

    f32x4 acc[6][2];
    #pragma unroll
    for (int ot = 0; ot < 6; ot++)
        #pragma unroll
        for (int nt = 0; nt < 2; nt++)
            acc[ot][nt] = (f32x4){0.f, 0.f, 0.f, 0.f};

    #pragma unroll
    for (int kk = 0; kk < 8; kk++) {
        const bf16x8 bf0 = *(const bf16x8*)&sh.x_t[c16     ][kk*32 + 8*q];
        const bf16x8 bf1 = *(const bf16x8*)&sh.x_t[16 + c16][kk*32 + 8*q];
        #pragma unroll
        for (int ot = 0; ot < 6; ot++) {
            const int o = 16*(4*ot + w) + c16;
            const bf16x8 af = *(const bf16x8*)&wbf[(size_t)o*C_IN + kk*32 + 8*q];
            acc[ot][0] = MFMA32(af, bf0, acc[ot][0]);
            acc[ot][1] = MFMA32(af, bf1, acc[ot][1]);
        }
    }
    __syncthreads();   // x_t dead; reuse LDS for epilogue staging

    #pragma unroll
    for (int ot = 0; ot < 6; ot++) {
        const int T  = 4*ot + w;
        const int ob = 16*T + 4*q;
        float b0 = bias[ob+0], b1 = bias[ob+1], b2 = bias[ob+2], b3 = bias[ob+3];
        #pragma unroll
        for (int nt = 0; nt < 2; nt++) {
            const f32x4 a = acc[ot][nt];
            const float v0 = a[0]+b0, v1 = a[1]+b1, v2 = a[2]+b2, v3 = a[3]+b3;
            if (ot < 2) {
                uint2 u;
                u.x = (u32)f2bf(v0) | ((u32)f2bf(v1) << 16);
                u.y = (u32)f2bf(v2) | ((u32)f2bf(v3) << 16);
                *(uint2*)&sh.ep.qk[16*nt + c16][16*T + 4*q] = u;
            } else {
                const int cb = 16*T - 128 + 4*q;
                sh.ep.vl[cb+0][16*nt + c16] = f2bf(v0);
                sh.ep.vl[cb+1][16*nt + c16] = f2bf(v1);
                sh.ep.vl[cb+2][16*nt + c16] = f2bf(v2);
                sh.ep.vl[cb+3][16*nt + c16] = f2bf(v3);
            }
        }
    }
    __syncthreads();

    {   // coalesced global stores
        const int n  = t >> 3;
        const int o8 = (t & 7) * 8;
        *(uint4*)&qT[((size_t)b*NPT + n0 + n)*CQD + o8] = *(uint4*)&sh.ep.qk[n][o8];
        *(uint4*)&kT[((size_t)b*NPT + n0 + n)*CQD + o8] = *(uint4*)&sh.ep.qk[n][64 + o8];
        u16* vrow = &vbf[((size_t)b*C_IN + t)*NPT + n0];
        #pragma unroll
        for (int j = 0; j < 4; j++)
            *(uint4*)&vrow[8*j] = *(uint4*)&sh.ep.vl[t][8*j];
    }
}

// ---------------------------------------------------------------------------
// stats: no-max partial softmax sums over 1024-wide m-split via MFMA.
// grid (4 msplit, N/64, B), block 256.
// ---------------------------------------------------------------------------
__global__ __launch_bounds__(256) void stats_kernel(
    const u16* __restrict__ qT, const u16* __restrict__ kT,
    float* __restrict__ psum)
{
    const int t = threadIdx.x;
    const int w = t >> 6, l = t & 63, q = l >> 4, c16 = l & 15;
    const int ms = blockIdx.x, nt = blockIdx.y, b = blockIdx.z;
    const int nb = nt*64 + 16*w;

    const bf16x8* qp = (const bf16x8*)&qT[((size_t)b*NPT + nb + c16)*CQD + 8*q];
    const bf16x8 aq0 = qp[0];
    const bf16x8 aq1 = qp[4];

    float rz[4] = {0.f, 0.f, 0.f, 0.f};

    for (int m0 = ms*1024; m0 < ms*1024 + 1024; m0 += 64) {
        f32x4 s[4];
        #pragma unroll
        for (int mj = 0; mj < 4; mj++) {
            const bf16x8* kp = (const bf16x8*)&kT[((size_t)b*NPT + m0 + 16*mj + c16)*CQD + 8*q];
            f32x4 a = {0.f, 0.f, 0.f, 0.f};
            a = MFMA32(aq0, kp[0], a);
            a = MFMA32(aq1, kp[4], a);
            s[mj] = a;
        }
        #pragma unroll
        for (int r = 0; r < 4; r++) {
            rz[r] += EXP2F(s[0][r]*L2E) + EXP2F(s[1][r]*L2E)
                   + EXP2F(s[2][r]*L2E) + EXP2F(s[3][r]*L2E);
        }
    }
    #pragma unroll
    for (int r = 0; r < 4; r++) {
        float Z = rz[r];
        #pragma unroll
        for (int d = 1; d < 16; d <<= 1) Z += __shfl_xor(Z, d, 64);
        if (c16 == 0)
            psum[((size_t)(b*4 + ms))*NPT + nb + 4*q + r] = Z;
    }
}

// ---------------------------------------------------------------------------
// merge: Lrow[n] = log2(sum of 4 partial Z)
// ---------------------------------------------------------------------------
__global__ void merge_kernel(const float* __restrict__ psum, float* __restrict__ Lrow)
{
    const int g = blockIdx.x*256 + threadIdx.x;
    const int b = g >> 12;
    const int n = g & 4095;
    float Z = 0.f;
    #pragma unroll
    for (int s = 0; s < 4; s++) Z += psum[((size_t)(b*4+s))*NPT + n];
    Lrow[(size_t)b*NPT + n] = __log2f(Z);
}

// ---------------------------------------------------------------------------
// attn: BARRIER-FREE loop, all-32x32x16. Block = 32 m x 128 c; wave =
// (c-half wc, n-parity np). Each wave: s for its own 32-n' chunk (A=q, B=k,
// redundant across wc), exp in C-regs, lane-swap (shfl_xor 32) to convert
// C-layout -> B-fragment, PV for its 2 c-blocks. s redundancy x4 total.
// End: LDS reduction between n-parity wave pairs + residual epilogue.
// grid 1024 flat (b = id&3 -> XCD-pinned slabs), block 256.
// ---------------------------------------------------------------------------
__global__ __launch_bounds__(256, 4) void attn_kernel(
    const u16* __restrict__ qT, const u16* __restrict__ kT, const u16* __restrict__ vbf,
    const float* __restrict__ Lrow, const float* __restrict__ gamma,
    const float* __restrict__ x, float* __restrict__ out)
{
    __shared__ float red[2][64][36];   // [wc][lane][32 acc +pad] = 18.4 KB

    const int t  = threadIdx.x;
    const int w  = t >> 6, l = t & 63;
    const int l5 = l >> 5, lm = l & 31;
    const int wc = w & 1, np = w >> 1;

    const int id = blockIdx.x;               // 0..1023
    const int b  = id & 3;                   // XCD-pinned (ids = k mod 8 -> b = k&3)
    const int cs = (id >> 2) & 1;
    const int mt = id >> 3;                  // 0..127
    const int m0 = mt * 32;

    // k B-fragments (s stage): col = m0+lm, k = 16*ks + 8*l5 + e
    bf16x8 kf[4];
    #pragma unroll
    for (int ks = 0; ks < 4; ks++)
        kf[ks] = *(const bf16x8*)&kT[((size_t)b*NPT + m0 + lm)*CQD + 16*ks + 8*l5];

    f32x16 acc[2];   // [cq]: c = cs*128 + wc*64 + 32*cq + row(r), m = m0 + lm
    #pragma unroll
    for (int cq = 0; cq < 2; cq++)
        #pragma unroll
        for (int r = 0; r < 16; r++) acc[cq][r] = 0.f;

    const u16*   qbase = &qT[((size_t)b*NPT + lm)*CQD + 8*l5];
    const u16*   vbase = &vbf[((size_t)(b*C_IN + cs*128 + wc*64 + lm))*NPT + 8*l5];
    const float* Lbase = &Lrow[(size_t)b*NPT + 4*l5];

    for (int ntc = np; ntc < 128; ntc += 2) {
        const int n0 = ntc * 32;

        // q A-frags: row = n0+lm, k = 16*ks + 8*l5 + e
        bf16x8 qa[4];
        #pragma unroll
        for (int ks = 0; ks < 4; ks++)
            qa[ks] = *(const bf16x8*)(qbase + (size_t)n0*CQD + 16*ks);

        // s: 32 n' x 32 m (rows=n' via A=q, cols=m via B=k)
        f32x16 s;
        #pragma unroll
        for (int r = 0; r < 16; r++) s[r] = 0.f;
        #pragma unroll
        for (int ks = 0; ks < 4; ks++) s = MFMA3216(qa[ks], kf[ks], s);

        // Lrow for this lane's 16 rows: row(r) = (r&3) + 8*(r>>2) + 4*l5
        float4 Lr[4];
        #pragma unroll
        for (int g = 0; g < 4; g++)
            Lr[g] = *(const float4*)(Lbase + n0 + 8*g);

        // v A-frags: row = c, k = n' = 16*ks2 + 8*l5 + e
        bf16x8 va[2][2];
        #pragma unroll
        for (int cq = 0; cq < 2; cq++)
            #pragma unroll
            for (int ks2 = 0; ks2 < 2; ks2++)
                va[cq][ks2] = *(const bf16x8*)(vbase + (size_t)(32*cq)*NPT + n0 + 16*ks2);

        // p = exp2(s*L2E - L), trunc-pack pairs of consecutive rows
        u32 pk[8];
        #pragma unroll
        for (int g = 0; g < 4; g++) {
            const float p0 = EXP2F(s[4*g+0]*L2E - Lr[g].x);
            const float p1 = EXP2F(s[4*g+1]*L2E - Lr[g].y);
            const float p2 = EXP2F(s[4*g+2]*L2E - Lr[g].z);
            const float p3 = EXP2F(s[4*g+3]*L2E - Lr[g].w);
            pk[2*g]   = pack_trunc(p0, p1);   // rows 8g+4*l5 + {0,1}
            pk[2*g+1] = pack_trunc(p2, p3);   // rows 8g+4*l5 + {2,3}
        }
        // partner halves live in lane l^32
        u32 sh[8];
        #pragma unroll
        for (int j = 0; j < 8; j++)
            sh[j] = (u32)__shfl_xor((int)pk[j], 32, 64);

        // build B-frags (k = n') and PV
        #pragma unroll
        for (int ks2 = 0; ks2 < 2; ks2++) {
            uint4 fu;
            fu.x = l5 ? sh[4*ks2+2] : pk[4*ks2  ];
            fu.y = l5 ? sh[4*ks2+3] : pk[4*ks2+1];
            fu.z = l5 ? pk[4*ks2+2] : sh[4*ks2  ];
            fu.w = l5 ? pk[4*ks2+3] : sh[4*ks2+1];
            const bf16x8 pf = *(bf16x8*)&fu;
            acc[0] = MFMA3216(va[0][ks2], pf, acc[0]);
            acc[1] = MFMA3216(va[1][ks2], pf, acc[1]);
        }
    }

    // reduce n-parity wave pairs via LDS, then fused residual epilogue
    if (np == 1) {
        #pragma unroll
        for (int cq = 0; cq < 2; cq++)
            #pragma unroll
            for (int g = 0; g < 4; g++)
                *(f32x4*)&red[wc][l][16*cq + 4*g] =
                    (f32x4){acc[cq][4*g], acc[cq][4*g+1], acc[cq][4*g+2], acc[cq][4*g+3]};
    }
    __syncthreads();
    if (np == 0) {
        const float gm = gamma[0];
        #pragma unroll
        for (int cq = 0; cq < 2; cq++) {
            const int cb = cs*128 + wc*64 + 32*cq + 4*l5;
            #pragma unroll
            for (int r = 0; r < 16; r++) {
                const float pr = red[wc][l][16*cq + r];
                const int c = cb + (r & 3) + 8*(r >> 2);
                const size_t o = ((size_t)(b*C_IN + c))*NPT + m0 + lm;
                out[o] = gm*(acc[cq][r] + pr) + x[o];
            }
        }
    }
}

// ---------------------------------------------------------------------------
extern "C" void kernel_launch(void* const* d_in, const int* in_sizes, int n_in,
                              void* d_out, int out_size, void* d_ws, size_t ws_size,
                              hipStream_t stream)
{
    const float* x     = (const float*)d_in[0];
    const float* wq    = (const float*)d_in[1];
    const float* bq    = (const float*)d_in[2];
    const float* wk    = (const float*)d_in[3];
    const float* bk    = (const float*)d_in[4];
    const float* wv    = (const float*)d_in[5];
    const float* bv    = (const float*)d_in[6];
    const float* gamma = (const float*)d_in[7];
    float* out = (float*)d_out;

    u16* qT  = (u16*)d_ws;                              // 2 MB
    u16* kT  = qT  + (size_t)NB*NPT*CQD;                // 2 MB
    u16* vbf = kT  + (size_t)NB*NPT*CQD;                // 8 MB
    u16* wbf = vbf + (size_t)NB*C_IN*NPT;               // 192 KB
    float* fp    = (float*)(wbf + 384*256);
    float* bias  = fp;                                  // 384
    float* psum  = bias + 384;                          // 64 KB
    float* Lrow  = psum + (size_t)NB*4*NPT;             // 64 KB

    prep_kernel<<<dim3(386), 256, 0, stream>>>(wq, bq, wk, bk, wv, bv, wbf, bias);
    proj_kernel<<<dim3(NPT/32, NB), 256, 0, stream>>>(x, wbf, bias, qT, kT, vbf);
    stats_kernel<<<dim3(4, NPT/64, NB), 256, 0, stream>>>(qT, kT, psum);
    merge_kernel<<<dim3(64), 256, 0, stream>>>(psum, Lrow);
    attn_kernel<<<dim3(1024), 256, 0, stream>>>(qT, kT, vbf, Lrow, gamma, x, out);
}

// Round 9
// 343.813 us; speedup vs baseline: 1.2127x; 1.2127x over previous
//
#include <hip/hip_runtime.h>

#define NB   4
#define C_IN 256
#define CQD  64
#define NPT  4096
#define L2E  1.44269504088896f

typedef __attribute__((ext_vector_type(8)))  short bf16x8;
typedef __attribute__((ext_vector_type(4)))  float f32x4;
typedef __attribute__((ext_vector_type(16))) float f32x16;
typedef unsigned short u16;
typedef unsigned int   u32;

#define EXP2F(x)        __builtin_amdgcn_exp2f(x)
#define MFMA32(A,B,C)   __builtin_amdgcn_mfma_f32_16x16x32_bf16(A,B,C,0,0,0)
#define MFMA3216(A,B,C) __builtin_amdgcn_mfma_f32_32x32x16_bf16(A,B,C,0,0,0)

__device__ __forceinline__ u16 f2bf(float f) {          // RNE (cold paths)
    u32 u = __float_as_uint(f);
    u += 0x7fff + ((u >> 16) & 1);
    return (u16)(u >> 16);
}
// one v_perm: (bf16_trunc(hi)<<16) | bf16_trunc(lo)
__device__ __forceinline__ u32 pack_trunc(float lo, float hi) {
    return __builtin_amdgcn_perm(__float_as_uint(hi), __float_as_uint(lo), 0x07060302u);
}

// ---------------------------------------------------------------------------
// prep: pack wq|wk|wv into bf16 wbf[384][256], biases into bias[384]
// ---------------------------------------------------------------------------
__global__ void prep_kernel(
    const float* __restrict__ wq, const float* __restrict__ bq,
    const float* __restrict__ wk, const float* __restrict__ bk,
    const float* __restrict__ wv, const float* __restrict__ bv,
    u16* __restrict__ wbf, float* __restrict__ bias)
{
    const int gid = blockIdx.x*256 + threadIdx.x;
    if (gid < 384*256) {
        const int r = gid >> 8, c = gid & 255;
        const float v = (r < 64) ? wq[r*256 + c]
                      : (r < 128) ? wk[(r-64)*256 + c]
                                  : wv[(r-128)*256 + c];
        wbf[gid] = f2bf(v);
    } else if (gid < 384*256 + 384) {
        const int r = gid - 384*256;
        bias[r] = (r < 64) ? bq[r] : (r < 128) ? bk[r-64] : bv[r-128];
    }
}

// ---------------------------------------------------------------------------
// proj: MFMA pointwise projections, x read ONCE. 512-thread blocks (8 waves,
// 4 waves/SIMD at 2 blocks/CU). Wave w owns tiles T = 8*ot + w.
// grid (N/32, B), block 512.
// ---------------------------------------------------------------------------
union ProjShared {
    u16 x_t[32][264];                            // [n][c] bf16, stride 528B
    struct { u16 qk[32][136]; u16 vl[256][40]; } ep;
};

__global__ __launch_bounds__(512) void proj_kernel(
    const float* __restrict__ x, const u16* __restrict__ wbf,
    const float* __restrict__ bias,
    u16* __restrict__ qT, u16* __restrict__ kT, u16* __restrict__ vbf)
{
    __shared__ ProjShared sh;

    const int t  = threadIdx.x;
    const int n0 = blockIdx.x * 32;
    const int b  = blockIdx.y;

    {   // stage x tile transposed -> bf16 LDS (16 elems/thread)
        const int ln = t & 31;
        const int cg = t >> 5;       // 0..15
        #pragma unroll
        for (int rr = 0; rr < 4; rr++) {
            const int c = 4*cg + 64*rr;
            const float f0 = x[((size_t)(b*C_IN + c+0))*NPT + n0 + ln];
            const float f1 = x[((size_t)(b*C_IN + c+1))*NPT + n0 + ln];
            const float f2 = x[((size_t)(b*C_IN + c+2))*NPT + n0 + ln];
            const float f3 = x[((size_t)(b*C_IN + c+3))*NPT + n0 + ln];
            ushort4 u4;
            u4.x = f2bf(f0); u4.y = f2bf(f1); u4.z = f2bf(f2); u4.w = f2bf(f3);
            *(ushort4*)&sh.x_t[ln][c] = u4;
        }
    }
    __syncthreads();

    const int w = t >> 6, l = t & 63, q = l >> 4, c16 = l & 15;

    f32x4 acc[3][2];
    #pragma unroll
    for (int ot = 0; ot < 3; ot++)
        #pragma unroll
        for (int nt = 0; nt < 2; nt++)
            acc[ot][nt] = (f32x4){0.f, 0.f, 0.f, 0.f};

    #pragma unroll
    for (int kk = 0; kk < 8; kk++) {
        const bf16x8 bf0 = *(const bf16x8*)&sh.x_t[c16     ][kk*32 + 8*q];
        const bf16x8 bf1 = *(const bf16x8*)&sh.x_t[16 + c16][kk*32 + 8*q];
        #pragma unroll
        for (int ot = 0; ot < 3; ot++) {
            const int o = 16*(8*ot + w) + c16;
            const bf16x8 af = *(const bf16x8*)&wbf[(size_t)o*C_IN + kk*32 + 8*q];
            acc[ot][0] = MFMA32(af, bf0, acc[ot][0]);
            acc[ot][1] = MFMA32(af, bf1, acc[ot][1]);
        }
    }
    __syncthreads();   // x_t dead; reuse LDS for epilogue staging

    #pragma unroll
    for (int ot = 0; ot < 3; ot++) {
        const int T  = 8*ot + w;
        const int ob = 16*T + 4*q;
        float b0 = bias[ob+0], b1 = bias[ob+1], b2 = bias[ob+2], b3 = bias[ob+3];
        #pragma unroll
        for (int nt = 0; nt < 2; nt++) {
            const f32x4 a = acc[ot][nt];
            const float v0 = a[0]+b0, v1 = a[1]+b1, v2 = a[2]+b2, v3 = a[3]+b3;
            if (ot == 0) {
                uint2 u;
                u.x = (u32)f2bf(v0) | ((u32)f2bf(v1) << 16);
                u.y = (u32)f2bf(v2) | ((u32)f2bf(v3) << 16);
                *(uint2*)&sh.ep.qk[16*nt + c16][ob] = u;
            } else {
                const int cb = 16*T - 128 + 4*q;
                sh.ep.vl[cb+0][16*nt + c16] = f2bf(v0);
                sh.ep.vl[cb+1][16*nt + c16] = f2bf(v1);
                sh.ep.vl[cb+2][16*nt + c16] = f2bf(v2);
                sh.ep.vl[cb+3][16*nt + c16] = f2bf(v3);
            }
        }
    }
    __syncthreads();

    {   // coalesced global stores (512 threads)
        const int n  = t >> 4;            // 0..31
        const int o8 = (t & 15) * 8;      // 0..120
        const uint4 qkv = *(uint4*)&sh.ep.qk[n][o8];
        if (o8 < 64)
            *(uint4*)&qT[((size_t)b*NPT + n0 + n)*CQD + o8] = qkv;
        else
            *(uint4*)&kT[((size_t)b*NPT + n0 + n)*CQD + (o8 - 64)] = qkv;

        const int c = t >> 1, hf = (t & 1) * 16;
        u16* vrow = &vbf[((size_t)b*C_IN + c)*NPT + n0 + hf];
        *(uint4*)&vrow[0] = *(uint4*)&sh.ep.vl[c][hf];
        *(uint4*)&vrow[8] = *(uint4*)&sh.ep.vl[c][hf + 8];
    }
}

// ---------------------------------------------------------------------------
// stats: no-max partial softmax sums over 1024-wide m-split via MFMA.
// grid (4 msplit, N/64, B), block 256.
// ---------------------------------------------------------------------------
__global__ __launch_bounds__(256) void stats_kernel(
    const u16* __restrict__ qT, const u16* __restrict__ kT,
    float* __restrict__ psum)
{
    const int t = threadIdx.x;
    const int w = t >> 6, l = t & 63, q = l >> 4, c16 = l & 15;
    const int ms = blockIdx.x, nt = blockIdx.y, b = blockIdx.z;
    const int nb = nt*64 + 16*w;

    const bf16x8* qp = (const bf16x8*)&qT[((size_t)b*NPT + nb + c16)*CQD + 8*q];
    const bf16x8 aq0 = qp[0];
    const bf16x8 aq1 = qp[4];

    float rz[4] = {0.f, 0.f, 0.f, 0.f};

    for (int m0 = ms*1024; m0 < ms*1024 + 1024; m0 += 64) {
        f32x4 s[4];
        #pragma unroll
        for (int mj = 0; mj < 4; mj++) {
            const bf16x8* kp = (const bf16x8*)&kT[((size_t)b*NPT + m0 + 16*mj + c16)*CQD + 8*q];
            f32x4 a = {0.f, 0.f, 0.f, 0.f};
            a = MFMA32(aq0, kp[0], a);
            a = MFMA32(aq1, kp[4], a);
            s[mj] = a;
        }
        #pragma unroll
        for (int r = 0; r < 4; r++) {
            rz[r] += EXP2F(s[0][r]*L2E) + EXP2F(s[1][r]*L2E)
                   + EXP2F(s[2][r]*L2E) + EXP2F(s[3][r]*L2E);
        }
    }
    #pragma unroll
    for (int r = 0; r < 4; r++) {
        float Z = rz[r];
        #pragma unroll
        for (int d = 1; d < 16; d <<= 1) Z += __shfl_xor(Z, d, 64);
        if (c16 == 0)
            psum[((size_t)(b*4 + ms))*NPT + nb + 4*q + r] = Z;
    }
}

// ---------------------------------------------------------------------------
// merge: Lrow[n] = log2(sum of 4 partial Z)
// ---------------------------------------------------------------------------
__global__ void merge_kernel(const float* __restrict__ psum, float* __restrict__ Lrow)
{
    const int g = blockIdx.x*256 + threadIdx.x;
    const int b = g >> 12;
    const int n = g & 4095;
    float Z = 0.f;
    #pragma unroll
    for (int s = 0; s < 4; s++) Z += psum[((size_t)(b*4+s))*NPT + n];
    Lrow[(size_t)b*NPT + n] = __log2f(Z);
}

// ---------------------------------------------------------------------------
// attn: 512-thread blocks (8 waves = 4/SIMD at 2 blocks/CU), 64m x 128c,
// 128-n' chunks. s stage: wave (wn=w>>1, wm=w&1) computes 32n'x32m via
// 32x32x16 (C/D rows = 4-consecutive-n' groups -> direct uint2 p writes).
// One barrier. PV stage: wave (wc=w>>1, wm2=w&1) computes 32c x 32m o-tile,
// 8 x 32x32x16 over K=128, B-frags from flat p layout U = k4*66 + m
// (k4 = n'/4, stride 66 units -> conflict-free b64 reads).
// grid 512 flat (b = id&3 -> XCD-pinned slabs), block 512.
// ---------------------------------------------------------------------------
__global__ __launch_bounds__(512, 4) void attn_kernel(
    const u16* __restrict__ qT, const u16* __restrict__ kT, const u16* __restrict__ vbf,
    const float* __restrict__ Lrow, const float* __restrict__ gamma,
    const float* __restrict__ x, float* __restrict__ out)
{
    __shared__ uint2 p_l[2][2112];   // 32 k4-rows x 66-unit stride, 16.9 KB x2

    const int t = threadIdx.x;
    const int w = t >> 6, l = t & 63;
    const int l5 = l >> 5, lm = l & 31;
    const int wn = w >> 1, wm = w & 1;      // s roles: n'-quarter, m-half
    const int wc = w >> 1, wm2 = w & 1;     // PV roles: c-quarter, m-half

    const int id = blockIdx.x;              // 0..511
    const int b  = id & 3;                  // XCD-pinned slabs
    const int cs = (id >> 2) & 1;
    const int mt = id >> 3;                 // 0..63
    const int m0 = mt * 64;

    // k B-fragments (s stage): col m = m0+32*wm+lm, k = 16*ks+8*l5+e
    bf16x8 kf[4];
    #pragma unroll
    for (int ks = 0; ks < 4; ks++)
        kf[ks] = *(const bf16x8*)&kT[((size_t)b*NPT + m0 + 32*wm + lm)*CQD + 16*ks + 8*l5];

    f32x16 acc;
    #pragma unroll
    for (int r = 0; r < 16; r++) acc[r] = 0.f;

    const u16*   qbase = &qT[((size_t)b*NPT + 32*wn + lm)*CQD + 8*l5];
    const u16*   vbase = &vbf[((size_t)(b*C_IN + cs*128 + 32*wc + lm))*NPT + 8*l5];
    const float* Lbase = &Lrow[(size_t)b*NPT + 32*wn + 4*l5];

    bf16x8 qa[4];
    #pragma unroll
    for (int ks = 0; ks < 4; ks++)
        qa[ks] = *(const bf16x8*)(qbase + 16*ks);

    int buf = 0;
    for (int nt = 0; nt < 32; nt++) {
        const int n0 = nt * 128;

        // s: 32 n' x 32 m (rows = n' via A=q, cols = m via B=k)
        f32x16 s;
        #pragma unroll
        for (int r = 0; r < 16; r++) s[r] = 0.f;
        #pragma unroll
        for (int ks = 0; ks < 4; ks++) s = MFMA3216(qa[ks], kf[ks], s);

        if (nt < 31) {   // prefetch next q A-frags
            #pragma unroll
            for (int ks = 0; ks < 4; ks++)
                qa[ks] = *(const bf16x8*)(qbase + (size_t)(n0 + 128)*CQD + 16*ks);
        }

        // p = exp2(s*L2E - L), pack 4 consecutive n' rows -> one uint2 unit
        #pragma unroll
        for (int g = 0; g < 4; g++) {
            const float4 Lr = *(const float4*)(Lbase + n0 + 8*g);
            const float p0 = EXP2F(s[4*g+0]*L2E - Lr.x);
            const float p1 = EXP2F(s[4*g+1]*L2E - Lr.y);
            const float p2 = EXP2F(s[4*g+2]*L2E - Lr.z);
            const float p3 = EXP2F(s[4*g+3]*L2E - Lr.w);
            uint2 u;
            u.x = pack_trunc(p0, p1);
            u.y = pack_trunc(p2, p3);
            p_l[buf][(8*wn + 2*g + l5)*66 + 32*wm + lm] = u;
        }
        __syncthreads();

        // PV: 8 k-steps of 32x32x16 over this 128-n' chunk
        #pragma unroll
        for (int st = 0; st < 8; st++) {
            const bf16x8 va = *(const bf16x8*)(vbase + n0 + 16*st);
            const uint2 e0 = p_l[buf][(4*st + 2*l5    )*66 + 32*wm2 + lm];
            const uint2 e1 = p_l[buf][(4*st + 2*l5 + 1)*66 + 32*wm2 + lm];
            uint4 fu = make_uint4(e0.x, e0.y, e1.x, e1.y);
            acc = MFMA3216(va, *(bf16x8*)&fu, acc);
        }
        buf ^= 1;
    }

    // epilogue: C/D 32x32 layout col = lm, row = (r&3)+8*(r>>2)+4*l5
    const float gm = gamma[0];
    #pragma unroll
    for (int r = 0; r < 16; r++) {
        const int c = cs*128 + 32*wc + (r & 3) + 8*(r >> 2) + 4*l5;
        const size_t o = ((size_t)(b*C_IN + c))*NPT + m0 + 32*wm2 + lm;
        out[o] = gm*acc[r] + x[o];
    }
}

// ---------------------------------------------------------------------------
extern "C" void kernel_launch(void* const* d_in, const int* in_sizes, int n_in,
                              void* d_out, int out_size, void* d_ws, size_t ws_size,
                              hipStream_t stream)
{
    const float* x     = (const float*)d_in[0];
    const float* wq    = (const float*)d_in[1];
    const float* bq    = (const float*)d_in[2];
    const float* wk    = (const float*)d_in[3];
    const float* bk    = (const float*)d_in[4];
    const float* wv    = (const float*)d_in[5];
    const float* bv    = (const float*)d_in[6];
    const float* gamma = (const float*)d_in[7];
    float* out = (float*)d_out;

    u16* qT  = (u16*)d_ws;                              // 2 MB
    u16* kT  = qT  + (size_t)NB*NPT*CQD;                // 2 MB
    u16* vbf = kT  + (size_t)NB*NPT*CQD;                // 8 MB
    u16* wbf = vbf + (size_t)NB*C_IN*NPT;               // 192 KB
    float* fp    = (float*)(wbf + 384*256);
    float* bias  = fp;                                  // 384
    float* psum  = bias + 384;                          // 64 KB
    float* Lrow  = psum + (size_t)NB*4*NPT;             // 64 KB

    prep_kernel<<<dim3(386), 256, 0, stream>>>(wq, bq, wk, bk, wv, bv, wbf, bias);
    proj_kernel<<<dim3(NPT/32, NB), 512, 0, stream>>>(x, wbf, bias, qT, kT, vbf);
    stats_kernel<<<dim3(4, NPT/64, NB), 256, 0, stream>>>(qT, kT, psum);
    merge_kernel<<<dim3(64), 256, 0, stream>>>(psum, Lrow);
    attn_kernel<<<dim3(512), 512, 0, stream>>>(qT, kT, vbf, Lrow, gamma, x, out);
}